// Round 12
// baseline (288.496 us; speedup 1.0000x reference)
//
#include <hip/hip_runtime.h>
#include <cmath>

#define NN 100000   // nodes
#define FF 256      // feature dim
#define DDIM 128    // embedding dim
#define MM 10       // categories
#define BB 32768    // batch
#define KK 32       // neighbors
#define NB1 1563    // k1/kW blocks (64 rows each)
#define NREP 64     // ce replicas

// workspace layout (float offsets)
#define OFF_Q     0          // [NN] q
#define OFF_CEREP 100096     // [64][1280] ce replicas (memset 0 each launch)
#define OFF_CE    182016     // [10][128] reduced ce
#define OFF_LAT   183296     // [20][128] sigmoid lat table
#define OFF_CE01  185856     // [2][128] ce rows 0,1 in p-space
#define OFF_CS    186112     // [2] c0,c1 (+pad)
#define OFF_AGGB  186128     // [BB][128] bf16 (2,097,152 floats)
#define OFF_FE8   2283280    // [NN][128] bytes fp8 e4m3, p-space cols
#define OFF_WF    5483280    // W_emb bf16 frags (32768 shorts = 16384 floats)
#define OFF_WPF   5499664    // Wp bf16 frags, p-space k rows (16384 shorts)
#define OFF_AF    5507856    // feat bf16 A-frags [NB1*4][8][512] shorts (12,804,096 floats)
// total 18,311,952 floats = 69.9 MiB

typedef __attribute__((ext_vector_type(8))) short bf16x8;
typedef __attribute__((ext_vector_type(4))) float floatx4;
typedef __attribute__((ext_vector_type(2))) float floatx2;

__device__ __forceinline__ unsigned short f2bf(float x) {
  union { float f; unsigned u; } v; v.f = x;
  unsigned r = v.u + 0x7FFFu + ((v.u >> 16) & 1u);   // RNE
  return (unsigned short)(r >> 16);
}

__device__ __forceinline__ bf16x8 cvt8(float4 a, float4 b) {
  short h[8];
  h[0] = (short)f2bf(a.x); h[1] = (short)f2bf(a.y);
  h[2] = (short)f2bf(a.z); h[3] = (short)f2bf(a.w);
  h[4] = (short)f2bf(b.x); h[5] = (short)f2bf(b.y);
  h[6] = (short)f2bf(b.z); h[7] = (short)f2bf(b.w);
  return *reinterpret_cast<bf16x8*>(h);
}

// ---------------------------------------------------------------------------
// k0: prep B-operand fragment tables (bf16, 16x16x32 layout).
//  t < 4096:  wf  <- W_emb [256][128]:    elem = W[kk*32+(l>>4)*8+j][ct*16+(l&15)]
//  t >= 4096: wpf <- Wp = l1w[:128]+l1w[128:], k-rows inverse-permuted (p-space)
// ---------------------------------------------------------------------------
__global__ __launch_bounds__(256) void k0_wprep(const float* __restrict__ wemb,
                                                const float* __restrict__ l1w,
                                                short* __restrict__ wf,
                                                short* __restrict__ wpf)
{
  const int t = blockIdx.x * 256 + threadIdx.x;   // 0..6143
  if (t < 4096) {
    const int kk = t >> 9, rem = t & 511;
    const int ct = rem >> 6, l = rem & 63;
    const int n = ct * 16 + (l & 15);
    const int kbase = kk * 32 + (l >> 4) * 8;
    short hi[8];
#pragma unroll
    for (int j = 0; j < 8; j++) hi[j] = (short)f2bf(wemb[(kbase + j) * 128 + n]);
    *reinterpret_cast<int4*>(&wf[((kk * 8 + ct) * 64 + l) * 8]) = *reinterpret_cast<int4*>(hi);
  } else {
    const int t2 = t - 4096;                      // 0..2047
    const int kk = t2 >> 9, rem = t2 & 511;
    const int ct = rem >> 6, l = rem & 63;
    const int n = ct * 16 + (l & 15);
    short h[8];
#pragma unroll
    for (int j = 0; j < 8; j++) {
      const int kp = kk * 32 + (l >> 4) * 8 + j;
      const int i = ((kp & 7) << 4) | (kp >> 3);  // inverse of p(i)=(i&15)*8+(i>>4)
      h[j] = (short)f2bf(l1w[i * 128 + n] + l1w[(128 + i) * 128 + n]);
    }
    *reinterpret_cast<int4*>(&wpf[((kk * 8 + ct) * 64 + l) * 8]) = *reinterpret_cast<int4*>(h);
  }
}

// ---------------------------------------------------------------------------
// kW: feat fp32 -> bf16 A-fragment layout (m13 copy shape on both ends).
// Per block: 64 rows in 4 panels of 16. Load: one ROW per wave-instruction
// (1 KB fully contiguous). LDS transpose (stride 65 float4 -> conflict-lite).
// Emit: af[(blk*4+g)*8+kk][lane][j] = feat[row=base+lane16][kk*32+quad*8+j],
// 1 KB contiguous per wave-instruction store.
// ---------------------------------------------------------------------------
__global__ __launch_bounds__(256) void kW_afrag(const float* __restrict__ feat,
                                                short* __restrict__ af)
{
  __shared__ __align__(16) float4 tile[16 * 65];
  const int tid = threadIdx.x;
  const int rowbase = blockIdx.x * 64;
#pragma unroll 1
  for (int g = 0; g < 4; g++) {
    if (g) __syncthreads();
#pragma unroll
    for (int i = 0; i < 4; i++) {
      const int idx = i * 256 + tid;            // 0..1023
      const int r16 = idx >> 6, f4 = idx & 63;  // wave covers ONE row contiguously
      int gr = rowbase + g * 16 + r16; if (gr > NN - 1) gr = NN - 1;
      tile[r16 * 65 + f4] = *reinterpret_cast<const float4*>(&feat[(size_t)gr * 256 + f4 * 4]);
    }
    __syncthreads();
#pragma unroll
    for (int i = 0; i < 2; i++) {
      const int item = i * 256 + tid;           // 0..511 = kk*64 + lane
      const int kk = item >> 6, lane = item & 63;
      const int lane16 = lane & 15, quad = lane >> 4;
      const float4 f0 = tile[lane16 * 65 + kk * 8 + quad * 2];
      const float4 f1 = tile[lane16 * 65 + kk * 8 + quad * 2 + 1];
      const bf16x8 a = cvt8(f0, f1);
      *reinterpret_cast<bf16x8*>(
          &af[(((size_t)blockIdx.x * 4 + g) * 8 + kk) * 512 + lane * 8]) = a;
    }
  }
}

// ---------------------------------------------------------------------------
// K1 (fused): 1563 blocks x 256 thr (4 waves); 64 rows/block, 16 rows/wave.
// A-operands register-direct from af (8 dwordx4/wave, L3-hot, issued upfront);
// B frags from wf (L2-hot) per kk. No staging LDS, no in-loop cvt.
// Epilogue: bias/q/fe8, cetile (18.4 KB LDS), adj-MFMA, cerep atomicAdd.
// ---------------------------------------------------------------------------
__global__ __launch_bounds__(256) void k1_fused(const short* __restrict__ af,
    const short* __restrict__ wf, const float* __restrict__ bemb,
    const float* __restrict__ attw, const float* __restrict__ adj,
    float* __restrict__ q, unsigned char* __restrict__ fe8,
    float* __restrict__ cerep)
{
  __shared__ __align__(16) unsigned char cetile[128 * 144];
  const int tid = threadIdx.x;
  const int wv = tid >> 6, l = tid & 63;
  const int lane16 = l & 15, quad = l >> 4;
  const int rowbase = blockIdx.x * 64;

  // all A-frags for this wave's 16 rows, issued upfront (8 KB in flight/wave)
  const short* afb = &af[(((size_t)blockIdx.x * 4 + wv) * 8) * 512 + l * 8];
  bf16x8 afr[8];
#pragma unroll
  for (int kk = 0; kk < 8; kk++)
    afr[kk] = *reinterpret_cast<const bf16x8*>(&afb[kk * 512]);

  floatx4 acc[8];
#pragma unroll
  for (int ct = 0; ct < 8; ct++) acc[ct] = floatx4{0.f, 0.f, 0.f, 0.f};

#pragma unroll
  for (int kk = 0; kk < 8; kk++) {
    const short* wb = &wf[kk * 4096 + l * 8];
#pragma unroll
    for (int ct = 0; ct < 8; ct++) {
      const bf16x8 bh = *reinterpret_cast<const bf16x8*>(&wb[ct * 512]);
      acc[ct] = __builtin_amdgcn_mfma_f32_16x16x32_bf16(afr[kk], bh, acc[ct], 0, 0, 0);
    }
  }

  // ---- epilogue. C layout: col = ct*16+lane16 -> p = lane16*8+ct,
  // row = rowbase + wv*16 + quad*4 + reg.
  float bembv[8], attwv[8];
#pragma unroll
  for (int ct = 0; ct < 8; ct++) {
    bembv[ct] = bemb[ct * 16 + lane16];
    attwv[ct] = attw[ct * 16 + lane16];
  }
#pragma unroll
  for (int reg = 0; reg < 4; reg++) {
    const int rr = rowbase + wv * 16 + quad * 4 + reg;
    float v[8]; float qp = 0.f;
#pragma unroll
    for (int ct = 0; ct < 8; ct++) {
      v[ct] = acc[ct][reg] + bembv[ct];
      qp = fmaf(v[ct], attwv[ct], qp);
    }
    acc[0][reg] = v[0]; acc[1][reg] = v[1]; acc[2][reg] = v[2]; acc[3][reg] = v[3];
    acc[4][reg] = v[4]; acc[5][reg] = v[5]; acc[6][reg] = v[6]; acc[7][reg] = v[7];
    qp += __shfl_xor(qp, 1, 16);
    qp += __shfl_xor(qp, 2, 16);
    qp += __shfl_xor(qp, 4, 16);
    qp += __shfl_xor(qp, 8, 16);
    if (rr < NN) {
      unsigned u0 = __builtin_amdgcn_cvt_pk_fp8_f32(v[0], v[1], 0, false);
      u0 = __builtin_amdgcn_cvt_pk_fp8_f32(v[2], v[3], u0, true);
      unsigned u1 = __builtin_amdgcn_cvt_pk_fp8_f32(v[4], v[5], 0, false);
      u1 = __builtin_amdgcn_cvt_pk_fp8_f32(v[6], v[7], u1, true);
      *reinterpret_cast<uint2*>(&fe8[(size_t)rr * 128 + lane16 * 8]) = make_uint2(u0, u1);
      if (lane16 == 0) q[rr] = 0.5f * qp;
    }
  }

  // cetile: bf16 [col][row0..63], col stride 144 B; zero rows >= NN
#pragma unroll
  for (int rp = 0; rp < 2; rp++) {
    const int rloc = wv * 16 + quad * 4 + rp * 2;
    const int g0 = rowbase + rloc;
#pragma unroll
    for (int ct = 0; ct < 8; ct++) {
      const unsigned short h0 = (g0     < NN) ? f2bf(acc[ct][rp * 2])     : (unsigned short)0;
      const unsigned short h1 = (g0 + 1 < NN) ? f2bf(acc[ct][rp * 2 + 1]) : (unsigned short)0;
      const unsigned pk = (unsigned)h0 | ((unsigned)h1 << 16);
      *reinterpret_cast<unsigned*>(&cetile[(ct * 16 + lane16) * 144 + rloc * 2]) = pk;
    }
  }
  __syncthreads();

  // ce partial: [10(pad16)][128] = adj[., block rows] @ tile -> cerep atomicAdd
  floatx4 cacc[2];
  cacc[0] = floatx4{0.f, 0.f, 0.f, 0.f};
  cacc[1] = floatx4{0.f, 0.f, 0.f, 0.f};
  const int mclamp = (lane16 < 10) ? lane16 : 9;
#pragma unroll
  for (int kc = 0; kc < 2; kc++) {
    int n0 = rowbase + kc * 32 + quad * 8;
    if (n0 > NN - 8) n0 = NN - 8;               // clamped garbage x zero tile rows
    const float4 f0 = *reinterpret_cast<const float4*>(&adj[(size_t)mclamp * NN + n0]);
    const float4 f1 = *reinterpret_cast<const float4*>(&adj[(size_t)mclamp * NN + n0 + 4]);
    const bf16x8 afr2 = cvt8(f0, f1);
#pragma unroll
    for (int tt = 0; tt < 2; tt++) {
      const int col = (wv * 2 + tt) * 16 + lane16;
      const bf16x8 bfr = *reinterpret_cast<const bf16x8*>(
          &cetile[col * 144 + (kc * 32 + quad * 8) * 2]);
      cacc[tt] = __builtin_amdgcn_mfma_f32_16x16x32_bf16(afr2, bfr, cacc[tt], 0, 0, 0);
    }
  }
  float* myrep = &cerep[(blockIdx.x & (NREP - 1)) * 1280];
#pragma unroll
  for (int tt = 0; tt < 2; tt++) {
#pragma unroll
    for (int reg = 0; reg < 4; reg++) {
      const int m = quad * 4 + reg;
      if (m < 10)
        atomicAdd(&myrep[m * 128 + (wv * 2 + tt) * 16 + lane16], cacc[tt][reg]);
    }
  }
}

// k3r: reduce 64 ce replicas -> ce[1280]
__global__ __launch_bounds__(256) void k3r_reduce(const float* __restrict__ cerep,
                                                  float* __restrict__ ce)
{
  const int o = blockIdx.x * 256 + threadIdx.x;   // 0..1279
  if (o < 1280) {
    float s = 0.f;
#pragma unroll 8
    for (int r = 0; r < NREP; r++) s += cerep[r * 1280 + o];
    ce[o] = s;
  }
}

// K3: blocks 0..19 lat rows from ce (L2-hot, 5 KB); block 20: ce01p, cs
__global__ __launch_bounds__(128) void k3_prep(const float* __restrict__ ce,
    const float* __restrict__ wchar, const float* __restrict__ attw,
    float* __restrict__ latTab, float* __restrict__ ce01p, float* __restrict__ cs)
{
  const int blk = blockIdx.x, tid = threadIdx.x;
  __shared__ float cec[128], cep[128];
  if (blk < 20) {
    const int c = blk / 10, p = blk % 10;
    cec[tid] = ce[c * 128 + tid];
    cep[tid] = ce[p * 128 + tid];
    __syncthreads();
    float s = 0.f;
#pragma unroll 4
    for (int j = 0; j < 128; j++) {
      s = fmaf(cec[j], wchar[j * 128 + tid], s);
      s = fmaf(cep[j], wchar[(128 + j) * 128 + tid], s);
    }
    latTab[blk * 128 + tid] = 1.f / (1.f + expf(-s));
  } else {
    const float s0 = ce[tid];
    const float s1 = ce[128 + tid];
    const int pidx = (tid & 15) * 8 + (tid >> 4);   // p(c)
    ce01p[pidx] = s0;
    ce01p[128 + pidx] = s1;
    cec[tid] = s0 * attw[tid];
    cep[tid] = s1 * attw[tid];
    __syncthreads();
    if (tid < 64) {
      float p0 = cec[tid] + cec[tid + 64];
      float p1 = cep[tid] + cep[tid + 64];
#pragma unroll
      for (int off = 32; off >= 1; off >>= 1) {
        p0 += __shfl_xor(p0, off);
        p1 += __shfl_xor(p1, off);
      }
      if (tid == 0) { cs[0] = 0.5f * p0; cs[1] = 0.5f * p1; }
    }
  }
}

// ---------------------------------------------------------------------------
// K4a: softmax over 32 neighbor scores + fp8 weighted row gather (p-space).
// One half-wave per b; lane t covers p-cols 4t..4t+3. agg stored bf16.
// ---------------------------------------------------------------------------
__global__ __launch_bounds__(256) void k4a_attn(const unsigned char* __restrict__ fe8,
    const float* __restrict__ q, const float* __restrict__ adj,
    const int* __restrict__ history, const float* __restrict__ cs,
    const float* __restrict__ attb_p, const float* __restrict__ ce01p,
    short* __restrict__ aggb)
{
  const int tid = threadIdx.x;
  const int lane = tid & 63;
  const int wv = tid >> 6;
  const int half = lane >> 5;
  const int t = lane & 31;
  const int b = blockIdx.x * 8 + wv * 2 + half;

  const int n_my = history[b * 32 + t];
  const float a0 = adj[n_my];
  const float a1 = adj[NN + n_my];
  const float sc = q[n_my] + a0 * cs[0] + a1 * cs[1] + attb_p[0];
  float m = sc;
#pragma unroll
  for (int off = 16; off >= 1; off >>= 1) m = fmaxf(m, __shfl_xor(m, off, 32));
  const float e = expf(sc - m);
  float sum = e;
#pragma unroll
  for (int off = 16; off >= 1; off >>= 1) sum += __shfl_xor(sum, off, 32);
  const float att = e / sum;
  float p0 = att * a0, p1 = att * a1;
#pragma unroll
  for (int off = 16; off >= 1; off >>= 1) {
    p0 += __shfl_xor(p0, off, 32);
    p1 += __shfl_xor(p1, off, 32);
  }

  float4 acc = make_float4(0.f, 0.f, 0.f, 0.f);
#pragma unroll
  for (int k = 0; k < 32; k++) {
    const int nk = __shfl(n_my, k, 32);
    const float ak = __shfl(att, k, 32);
    const unsigned u = *reinterpret_cast<const unsigned*>(&fe8[(size_t)nk * 128 + t * 4]);
    const floatx2 lo = __builtin_amdgcn_cvt_pk_f32_fp8(u, false);
    const floatx2 hi = __builtin_amdgcn_cvt_pk_f32_fp8(u, true);
    acc.x = fmaf(ak, lo[0], acc.x);
    acc.y = fmaf(ak, lo[1], acc.y);
    acc.z = fmaf(ak, hi[0], acc.z);
    acc.w = fmaf(ak, hi[1], acc.w);
  }
  const int col = t * 4;
  const float4 c0 = *reinterpret_cast<const float4*>(&ce01p[col]);
  const float4 c1 = *reinterpret_cast<const float4*>(&ce01p[128 + col]);
  const float ox = 0.5f * (acc.x + p0 * c0.x + p1 * c1.x);
  const float oy = 0.5f * (acc.y + p0 * c0.y + p1 * c1.y);
  const float oz = 0.5f * (acc.z + p0 * c0.z + p1 * c1.z);
  const float ow = 0.5f * (acc.w + p0 * c0.w + p1 * c1.w);
  const unsigned lo_ = (unsigned)f2bf(ox) | ((unsigned)f2bf(oy) << 16);
  const unsigned hi_ = (unsigned)f2bf(oz) | ((unsigned)f2bf(ow) << 16);
  *reinterpret_cast<uint2*>(&aggb[(size_t)b * 128 + col]) = make_uint2(lo_, hi_);
}

// ---------------------------------------------------------------------------
// K4b: out = relu(aggb @ wpf + l1b); pred_r/pred_n = dot(latTab rows, out).
// bf16 MFMA, no LDS; 4 waves x 32 rows; epilogue in C-layout.
// ---------------------------------------------------------------------------
__global__ __launch_bounds__(256) void k4b_mfma(const short* __restrict__ aggb,
    const short* __restrict__ wpf, const float* __restrict__ l1b,
    const float* __restrict__ latTab,
    const int* __restrict__ cr, const int* __restrict__ cn, const int* __restrict__ pa,
    float* __restrict__ out)
{
  const int tid = threadIdx.x;
  const int wv = tid >> 6, l = tid & 63;
  const int lane16 = l & 15, quad = l >> 4;
  const int rowbase = blockIdx.x * 128 + wv * 32;   // BB = 256*128 exact
  const int r0 = rowbase + lane16;
  const int r1 = r0 + 16;

  floatx4 acc[2][8];
#pragma unroll
  for (int rt = 0; rt < 2; rt++)
#pragma unroll
    for (int ct = 0; ct < 8; ct++) acc[rt][ct] = floatx4{0.f, 0.f, 0.f, 0.f};

#pragma unroll
  for (int kk = 0; kk < 4; kk++) {
    const bf16x8 a0 = *reinterpret_cast<const bf16x8*>(&aggb[(size_t)r0 * 128 + kk * 32 + quad * 8]);
    const bf16x8 a1 = *reinterpret_cast<const bf16x8*>(&aggb[(size_t)r1 * 128 + kk * 32 + quad * 8]);
    const short* wb = &wpf[kk * 4096 + l * 8];
#pragma unroll
    for (int ct = 0; ct < 8; ct++) {
      const bf16x8 bh = *reinterpret_cast<const bf16x8*>(&wb[ct * 512]);
      acc[0][ct] = __builtin_amdgcn_mfma_f32_16x16x32_bf16(a0, bh, acc[0][ct], 0, 0, 0);
      acc[1][ct] = __builtin_amdgcn_mfma_f32_16x16x32_bf16(a1, bh, acc[1][ct], 0, 0, 0);
    }
  }

  float bb[8];
#pragma unroll
  for (int ct = 0; ct < 8; ct++) bb[ct] = l1b[ct * 16 + lane16];
#pragma unroll
  for (int rt = 0; rt < 2; rt++) {
#pragma unroll
    for (int reg = 0; reg < 4; reg++) {
      const int r = rowbase + rt * 16 + quad * 4 + reg;
      const int ir  = (cr[r] * 10 + pa[r]) * 128;
      const int in_ = (cn[r] * 10 + pa[r]) * 128;
      float pr = 0.f, pn = 0.f;
#pragma unroll
      for (int ct = 0; ct < 8; ct++) {
        const float v = fmaxf(acc[rt][ct][reg] + bb[ct], 0.f);
        pr = fmaf(v, latTab[ir  + ct * 16 + lane16], pr);
        pn = fmaf(v, latTab[in_ + ct * 16 + lane16], pn);
      }
      pr += __shfl_xor(pr, 1, 16); pr += __shfl_xor(pr, 2, 16);
      pr += __shfl_xor(pr, 4, 16); pr += __shfl_xor(pr, 8, 16);
      pn += __shfl_xor(pn, 1, 16); pn += __shfl_xor(pn, 2, 16);
      pn += __shfl_xor(pn, 4, 16); pn += __shfl_xor(pn, 8, 16);
      if (lane16 == 0) { out[r] = pr; out[BB + r] = pn; }
    }
  }
}

extern "C" void kernel_launch(void* const* d_in, const int* in_sizes, int n_in,
                              void* d_out, int out_size, void* d_ws, size_t ws_size,
                              hipStream_t stream) {
  const float* feat  = (const float*)d_in[0];   // [N,F]
  const float* adj   = (const float*)d_in[1];   // [M,N]
  const int*   hist  = (const int*)d_in[2];     // [B,K]
  // d_in[3] item_id unused by reference
  const int*   cr    = (const int*)d_in[4];
  const int*   cn    = (const int*)d_in[5];
  const int*   pa    = (const int*)d_in[6];
  const float* wemb  = (const float*)d_in[7];   // [F,D]
  const float* bemb  = (const float*)d_in[8];   // [D]
  const float* wchar = (const float*)d_in[9];   // [2D,D]
  const float* attw  = (const float*)d_in[10];  // [D]
  const float* attb  = (const float*)d_in[11];  // [1]
  const float* l1w   = (const float*)d_in[12];  // [2D,D]
  const float* l1b   = (const float*)d_in[13];  // [D]
  float* out = (float*)d_out;
  float* ws  = (float*)d_ws;

  float* q     = ws + OFF_Q;
  float* cerep = ws + OFF_CEREP;
  float* ce    = ws + OFF_CE;
  float* lat   = ws + OFF_LAT;
  float* ce01p = ws + OFF_CE01;
  float* cs    = ws + OFF_CS;
  short* aggb  = (short*)(ws + OFF_AGGB);
  unsigned char* fe8 = (unsigned char*)(ws + OFF_FE8);
  short* wf    = (short*)(ws + OFF_WF);
  short* wpf   = (short*)(ws + OFF_WPF);
  short* af    = (short*)(ws + OFF_AF);

  hipMemsetAsync(cerep, 0, NREP * 1280 * sizeof(float), stream);
  k0_wprep<<<24, 256, 0, stream>>>(wemb, l1w, wf, wpf);
  kW_afrag<<<NB1, 256, 0, stream>>>(feat, af);
  k1_fused<<<NB1, 256, 0, stream>>>(af, wf, bemb, attw, adj, q, fe8, cerep);
  k3r_reduce<<<5, 256, 0, stream>>>(cerep, ce);
  k3_prep<<<21, 128, 0, stream>>>(ce, wchar, attw, lat, ce01p, cs);
  k4a_attn<<<4096, 256, 0, stream>>>(fe8, q, adj, hist, cs, attb, ce01p, aggb);
  k4b_mfma<<<256, 256, 0, stream>>>(aggb, wpf, l1b, lat, cr, cn, pa, out);
}

// Round 13
// 257.729 us; speedup vs baseline: 1.1194x; 1.1194x over previous
//
#include <hip/hip_runtime.h>
#include <cmath>

#define NN 100000   // nodes
#define FF 256      // feature dim
#define DDIM 128    // embedding dim
#define MM 10       // categories
#define BB 32768    // batch
#define KK 32       // neighbors
#define NB1 782     // k1 blocks (128 rows each)
#define NREP 64     // ce replicas

// workspace layout (float offsets)
#define OFF_Q     0          // [NN] q
#define OFF_CEREP 100096     // [64][1280] ce replicas (zeroed by k0 each launch)
#define OFF_LAT   183296     // [20][128] sigmoid lat table
#define OFF_CE01  185856     // [2][128] ce rows 0,1 in p-space
#define OFF_CS    186112     // [2] c0,c1 (+pad)
#define OFF_FE8   2283280    // [NN][128] bytes fp8 e4m3, p-space cols
#define OFF_WF    5483280    // W_emb bf16 frags (32768 shorts)
#define OFF_WPF   5499664    // Wp bf16 frags, p-space k rows (16384 shorts)
// total 5,507,856 floats = 21.0 MiB

typedef __attribute__((ext_vector_type(8))) short bf16x8;
typedef __attribute__((ext_vector_type(4))) float floatx4;
typedef __attribute__((ext_vector_type(2))) float floatx2;

__device__ __forceinline__ unsigned short f2bf(float x) {
  union { float f; unsigned u; } v; v.f = x;
  unsigned r = v.u + 0x7FFFu + ((v.u >> 16) & 1u);   // RNE
  return (unsigned short)(r >> 16);
}

__device__ __forceinline__ bf16x8 cvt8(float4 a, float4 b) {
  short h[8];
  h[0] = (short)f2bf(a.x); h[1] = (short)f2bf(a.y);
  h[2] = (short)f2bf(a.z); h[3] = (short)f2bf(a.w);
  h[4] = (short)f2bf(b.x); h[5] = (short)f2bf(b.y);
  h[6] = (short)f2bf(b.z); h[7] = (short)f2bf(b.w);
  return *reinterpret_cast<bf16x8*>(h);
}

// async 16B/lane global->LDS DMA (wave-uniform LDS base + lane*16)
__device__ __forceinline__ void gload_lds16(const float* g, void* l) {
  __builtin_amdgcn_global_load_lds(
      (const __attribute__((address_space(1))) void*)g,
      (__attribute__((address_space(3))) void*)l, 16, 0, 0);
}

// ---------------------------------------------------------------------------
// k0: prep B-operand fragment tables (bf16, 16x16x32 layout) + zero cerep.
//  t < 4096:  wf  <- W_emb [256][128]:    elem = W[kk*32+(l>>4)*8+j][ct*16+(l&15)]
//  t >= 4096: wpf <- Wp = l1w[:128]+l1w[128:], k-rows inverse-permuted (p-space)
// ---------------------------------------------------------------------------
__global__ __launch_bounds__(256) void k0_wprep(const float* __restrict__ wemb,
                                                const float* __restrict__ l1w,
                                                short* __restrict__ wf,
                                                short* __restrict__ wpf,
                                                float* __restrict__ cerep)
{
  const int t = blockIdx.x * 256 + threadIdx.x;   // 0..6143
  // zero the ce replica buffer (harness poisons ws each call)
  for (int i = t; i < NREP * 1280; i += 24 * 256) cerep[i] = 0.f;

  if (t < 4096) {
    const int kk = t >> 9, rem = t & 511;
    const int ct = rem >> 6, l = rem & 63;
    const int n = ct * 16 + (l & 15);
    const int kbase = kk * 32 + (l >> 4) * 8;
    short hi[8];
#pragma unroll
    for (int j = 0; j < 8; j++) hi[j] = (short)f2bf(wemb[(kbase + j) * 128 + n]);
    *reinterpret_cast<int4*>(&wf[((kk * 8 + ct) * 64 + l) * 8]) = *reinterpret_cast<int4*>(hi);
  } else {
    const int t2 = t - 4096;                      // 0..2047
    const int kk = t2 >> 9, rem = t2 & 511;
    const int ct = rem >> 6, l = rem & 63;
    const int n = ct * 16 + (l & 15);
    short h[8];
#pragma unroll
    for (int j = 0; j < 8; j++) {
      const int kp = kk * 32 + (l >> 4) * 8 + j;
      const int i = ((kp & 7) << 4) | (kp >> 3);  // inverse of p(i)=(i&15)*8+(i>>4)
      h[j] = (short)f2bf(l1w[i * 128 + n] + l1w[(128 + i) * 128 + n]);
    }
    *reinterpret_cast<int4*>(&wpf[((kk * 8 + ct) * 64 + l) * 8]) = *reinterpret_cast<int4*>(h);
  }
}

// ---------------------------------------------------------------------------
// K1 (fused, known-59.8µs structure): 782 blocks x 256 thr (4 waves);
// 128 rows/block, 32 rows/wave. feat staged via global_load_lds dbuf (16KB
// chunks). Compute: ds_read_b128 x2 -> cvt8 -> 16 MFMA/kk/wave. Epilogue:
// fe8/q, cetile (aliases staging LDS), ce partial MFMA -> cerep atomicAdd.
// ---------------------------------------------------------------------------
__global__ __launch_bounds__(256, 4) void k1_fused(const float* __restrict__ feat,
    const short* __restrict__ wf, const float* __restrict__ bemb,
    const float* __restrict__ attw, const float* __restrict__ adj,
    float* __restrict__ q, unsigned char* __restrict__ fe8,
    float* __restrict__ cerep)
{
  __shared__ __align__(16) unsigned char ldsraw[34816];  // 2x16KB staging | cetile 128x272
  const int tid = threadIdx.x;
  const int wv = tid >> 6, l = tid & 63;
  const int lane16 = l & 15, quad = l >> 4;
  const int rowbase = blockIdx.x * 128;

  // DMA source: lane covers row rowbase+wv*32+i*8+(l>>3), 16B chunk (l&7)
  size_t gsrc[4];
#pragma unroll
  for (int i = 0; i < 4; i++) {
    int r = rowbase + wv * 32 + i * 8 + (l >> 3);
    if (r > NN - 1) r = NN - 1;
    gsrc[i] = (size_t)r * 256 + (l & 7) * 4;
  }
#pragma unroll
  for (int i = 0; i < 4; i++)
    gload_lds16(&feat[gsrc[i]], ldsraw + wv * 4096 + i * 1024);

  floatx4 acc[2][8];
#pragma unroll
  for (int rt = 0; rt < 2; rt++)
#pragma unroll
    for (int ct = 0; ct < 8; ct++) acc[rt][ct] = floatx4{0.f, 0.f, 0.f, 0.f};

#pragma unroll 2
  for (int kk = 0; kk < 8; kk++) {
    __syncthreads();                     // drain DMA: chunk kk visible
    if (kk < 7) {                        // prefetch kk+1 into other buffer
      unsigned char* dst = ldsraw + ((kk + 1) & 1) * 16384 + wv * 4096;
#pragma unroll
      for (int i = 0; i < 4; i++)
        gload_lds16(&feat[gsrc[i] + (size_t)(kk + 1) * 32], dst + i * 1024);
    }
    const float* Ab = (const float*)(ldsraw + (kk & 1) * 16384);
    const short* wb = &wf[kk * 4096 + l * 8];
    bf16x8 bh[8];
#pragma unroll
    for (int ct = 0; ct < 8; ct++)
      bh[ct] = *reinterpret_cast<const bf16x8*>(&wb[ct * 512]);
    bf16x8 a[2];
#pragma unroll
    for (int rt = 0; rt < 2; rt++) {
      const int row_loc = wv * 32 + rt * 16 + lane16;
      const float4 f0 = *reinterpret_cast<const float4*>(&Ab[row_loc * 32 + quad * 8]);
      const float4 f1 = *reinterpret_cast<const float4*>(&Ab[row_loc * 32 + quad * 8 + 4]);
      a[rt] = cvt8(f0, f1);
    }
#pragma unroll
    for (int rt = 0; rt < 2; rt++)
#pragma unroll
      for (int ct = 0; ct < 8; ct++)
        acc[rt][ct] = __builtin_amdgcn_mfma_f32_16x16x32_bf16(a[rt], bh[ct], acc[rt][ct], 0, 0, 0);
  }

  // epilogue: bias, q, fe8. C layout: col = ct*16+lane16 -> p = lane16*8+ct,
  // row = rowbase + wv*32 + rt*16 + quad*4 + reg.
  float bembv[8], attwv[8];
#pragma unroll
  for (int ct = 0; ct < 8; ct++) {
    bembv[ct] = bemb[ct * 16 + lane16];
    attwv[ct] = attw[ct * 16 + lane16];
  }
#pragma unroll
  for (int rt = 0; rt < 2; rt++) {
#pragma unroll
    for (int reg = 0; reg < 4; reg++) {
      const int r = rowbase + wv * 32 + rt * 16 + quad * 4 + reg;
      float v[8]; float qp = 0.f;
#pragma unroll
      for (int ct = 0; ct < 8; ct++) {
        v[ct] = acc[rt][ct][reg] + bembv[ct];
        qp = fmaf(v[ct], attwv[ct], qp);
      }
#pragma unroll
      for (int ct = 0; ct < 8; ct++) acc[rt][ct][reg] = v[ct];
      qp += __shfl_xor(qp, 1, 16);
      qp += __shfl_xor(qp, 2, 16);
      qp += __shfl_xor(qp, 4, 16);
      qp += __shfl_xor(qp, 8, 16);
      if (r < NN) {
        unsigned u0 = __builtin_amdgcn_cvt_pk_fp8_f32(v[0], v[1], 0, false);
        u0 = __builtin_amdgcn_cvt_pk_fp8_f32(v[2], v[3], u0, true);
        unsigned u1 = __builtin_amdgcn_cvt_pk_fp8_f32(v[4], v[5], 0, false);
        u1 = __builtin_amdgcn_cvt_pk_fp8_f32(v[6], v[7], u1, true);
        *reinterpret_cast<uint2*>(&fe8[(size_t)r * 128 + lane16 * 8]) = make_uint2(u0, u1);
        if (lane16 == 0) q[r] = 0.5f * qp;
      }
    }
  }

  __syncthreads();   // done reading staging LDS; reuse as cetile
  // cetile: bf16 [col][row0..127], col stride 272 B; zero rows >= NN
#pragma unroll
  for (int rt = 0; rt < 2; rt++) {
    const int rlocBase = wv * 32 + rt * 16 + quad * 4;
    const int gBase = rowbase + rlocBase;
#pragma unroll
    for (int ct = 0; ct < 8; ct++) {
      unsigned short u[4];
#pragma unroll
      for (int reg = 0; reg < 4; reg++)
        u[reg] = (gBase + reg < NN) ? f2bf(acc[rt][ct][reg]) : (unsigned short)0;
      const unsigned lo_ = (unsigned)u[0] | ((unsigned)u[1] << 16);
      const unsigned hi_ = (unsigned)u[2] | ((unsigned)u[3] << 16);
      *reinterpret_cast<uint2*>(&ldsraw[(ct * 16 + lane16) * 272 + rlocBase * 2]) =
          make_uint2(lo_, hi_);
    }
  }
  __syncthreads();

  // ce partial: [10(pad16)][128] = adj[., block rows] @ tile -> cerep atomicAdd
  floatx4 cacc[2];
  cacc[0] = floatx4{0.f, 0.f, 0.f, 0.f};
  cacc[1] = floatx4{0.f, 0.f, 0.f, 0.f};
  const int mclamp = (lane16 < 10) ? lane16 : 9;
#pragma unroll
  for (int kc = 0; kc < 4; kc++) {
    int n0 = rowbase + kc * 32 + quad * 8;
    if (n0 > NN - 8) n0 = NN - 8;               // clamped garbage x zero tile rows
    const float4 f0 = *reinterpret_cast<const float4*>(&adj[(size_t)mclamp * NN + n0]);
    const float4 f1 = *reinterpret_cast<const float4*>(&adj[(size_t)mclamp * NN + n0 + 4]);
    const bf16x8 afr = cvt8(f0, f1);
#pragma unroll
    for (int tt = 0; tt < 2; tt++) {
      const int col = (wv * 2 + tt) * 16 + lane16;
      const bf16x8 bfr = *reinterpret_cast<const bf16x8*>(
          &ldsraw[col * 272 + (kc * 32 + quad * 8) * 2]);
      cacc[tt] = __builtin_amdgcn_mfma_f32_16x16x32_bf16(afr, bfr, cacc[tt], 0, 0, 0);
    }
  }
  float* myrep = &cerep[(blockIdx.x & (NREP - 1)) * 1280];
#pragma unroll
  for (int tt = 0; tt < 2; tt++) {
#pragma unroll
    for (int reg = 0; reg < 4; reg++) {
      const int m = quad * 4 + reg;
      if (m < 10)
        atomicAdd(&myrep[m * 128 + (wv * 2 + tt) * 16 + lane16], cacc[tt][reg]);
    }
  }
}

// K3 (merged reduction): blocks 0..19 lat rows; block 20: ce01p, cs.
// Each block reduces its needed ce rows directly over the 64 replicas.
__global__ __launch_bounds__(128) void k3_prep(const float* __restrict__ cerep,
    const float* __restrict__ wchar, const float* __restrict__ attw,
    float* __restrict__ latTab, float* __restrict__ ce01p, float* __restrict__ cs)
{
  const int blk = blockIdx.x, tid = threadIdx.x;
  __shared__ float cec[128], cep[128];
  if (blk < 20) {
    const int c = blk / 10, p = blk % 10;
    float sc_ = 0.f, sp_ = 0.f;
#pragma unroll 4
    for (int r = 0; r < NREP; r++) {
      sc_ += cerep[r * 1280 + c * 128 + tid];
      sp_ += cerep[r * 1280 + p * 128 + tid];
    }
    cec[tid] = sc_; cep[tid] = sp_;
    __syncthreads();
    float s = 0.f;
#pragma unroll 4
    for (int j = 0; j < 128; j++) {
      s = fmaf(cec[j], wchar[j * 128 + tid], s);
      s = fmaf(cep[j], wchar[(128 + j) * 128 + tid], s);
    }
    latTab[blk * 128 + tid] = 1.f / (1.f + expf(-s));
  } else {
    float s0 = 0.f, s1 = 0.f;
#pragma unroll 4
    for (int r = 0; r < NREP; r++) {
      s0 += cerep[r * 1280 + tid];
      s1 += cerep[r * 1280 + 128 + tid];
    }
    const int pidx = (tid & 15) * 8 + (tid >> 4);   // p(c)
    ce01p[pidx] = s0;
    ce01p[128 + pidx] = s1;
    cec[tid] = s0 * attw[tid];
    cep[tid] = s1 * attw[tid];
    __syncthreads();
    if (tid < 64) {
      float p0 = cec[tid] + cec[tid + 64];
      float p1 = cep[tid] + cep[tid + 64];
#pragma unroll
      for (int off = 32; off >= 1; off >>= 1) {
        p0 += __shfl_xor(p0, off);
        p1 += __shfl_xor(p1, off);
      }
      if (tid == 0) { cs[0] = 0.5f * p0; cs[1] = 0.5f * p1; }
    }
  }
}

// ---------------------------------------------------------------------------
// K4 (fused attn + out GEMM): 2048 blocks x 256 thr; 16 b's per block.
// Phase 1: per half-wave, 2 b's sequentially — softmax over 32 scores + fp8
// weighted gather (p-space); agg written bf16 into LDS tile [b_loc][col],
// stride 272 B (A-frag-readable). Phase 2: 16x128x128 GEMM vs wpf (each wave
// 2 ct-tiles), relu+bias, pred dots vs latTab; cross-wave reduction via LDS
// float atomics; lanes 0..15 store out.
// ---------------------------------------------------------------------------
__global__ __launch_bounds__(256) void k4_fused(const unsigned char* __restrict__ fe8,
    const float* __restrict__ q, const float* __restrict__ adj,
    const int* __restrict__ history, const float* __restrict__ cs,
    const float* __restrict__ attb_p, const float* __restrict__ ce01p,
    const short* __restrict__ wpf, const float* __restrict__ l1b,
    const float* __restrict__ latTab,
    const int* __restrict__ cr, const int* __restrict__ cn, const int* __restrict__ pa,
    float* __restrict__ out)
{
  __shared__ __align__(16) unsigned char aggT[16 * 272];  // bf16 [b_loc][col]
  __shared__ float s_pr[16], s_pn[16];
  const int tid = threadIdx.x;
  const int lane = tid & 63;
  const int wv = tid >> 6;
  const int half = lane >> 5;
  const int t = lane & 31;
  const int hw = wv * 2 + half;           // 0..7
  const int bbase = blockIdx.x * 16;

  if (tid < 16) { s_pr[tid] = 0.f; s_pn[tid] = 0.f; }

#pragma unroll
  for (int it = 0; it < 2; it++) {
    const int b_loc = hw * 2 + it;
    const int b = bbase + b_loc;
    const int n_my = history[b * 32 + t];
    const float a0 = adj[n_my];
    const float a1 = adj[NN + n_my];
    const float sc = q[n_my] + a0 * cs[0] + a1 * cs[1] + attb_p[0];
    float m = sc;
#pragma unroll
    for (int off = 16; off >= 1; off >>= 1) m = fmaxf(m, __shfl_xor(m, off, 32));
    const float e = expf(sc - m);
    float sum = e;
#pragma unroll
    for (int off = 16; off >= 1; off >>= 1) sum += __shfl_xor(sum, off, 32);
    const float att = e / sum;
    float p0 = att * a0, p1 = att * a1;
#pragma unroll
    for (int off = 16; off >= 1; off >>= 1) {
      p0 += __shfl_xor(p0, off, 32);
      p1 += __shfl_xor(p1, off, 32);
    }

    float4 acc = make_float4(0.f, 0.f, 0.f, 0.f);
#pragma unroll
    for (int k = 0; k < 32; k++) {
      const int nk = __shfl(n_my, k, 32);
      const float ak = __shfl(att, k, 32);
      const unsigned u = *reinterpret_cast<const unsigned*>(&fe8[(size_t)nk * 128 + t * 4]);
      const floatx2 lo = __builtin_amdgcn_cvt_pk_f32_fp8(u, false);
      const floatx2 hi = __builtin_amdgcn_cvt_pk_f32_fp8(u, true);
      acc.x = fmaf(ak, lo[0], acc.x);
      acc.y = fmaf(ak, lo[1], acc.y);
      acc.z = fmaf(ak, hi[0], acc.z);
      acc.w = fmaf(ak, hi[1], acc.w);
    }
    const int col = t * 4;
    const float4 c0 = *reinterpret_cast<const float4*>(&ce01p[col]);
    const float4 c1 = *reinterpret_cast<const float4*>(&ce01p[128 + col]);
    const float ox = 0.5f * (acc.x + p0 * c0.x + p1 * c1.x);
    const float oy = 0.5f * (acc.y + p0 * c0.y + p1 * c1.y);
    const float oz = 0.5f * (acc.z + p0 * c0.z + p1 * c1.z);
    const float ow = 0.5f * (acc.w + p0 * c0.w + p1 * c1.w);
    const unsigned lo_ = (unsigned)f2bf(ox) | ((unsigned)f2bf(oy) << 16);
    const unsigned hi_ = (unsigned)f2bf(oz) | ((unsigned)f2bf(ow) << 16);
    *reinterpret_cast<uint2*>(&aggT[b_loc * 272 + t * 8]) = make_uint2(lo_, hi_);
  }
  __syncthreads();

  // phase 2: out = relu(aggT @ wpf + l1b); preds vs latTab rows.
  const int lane16 = lane & 15, quad = lane >> 4;
  floatx4 acc2[2];
  acc2[0] = floatx4{0.f, 0.f, 0.f, 0.f};
  acc2[1] = floatx4{0.f, 0.f, 0.f, 0.f};
#pragma unroll
  for (int kk = 0; kk < 4; kk++) {
    const bf16x8 a = *reinterpret_cast<const bf16x8*>(
        &aggT[lane16 * 272 + (kk * 32 + quad * 8) * 2]);
#pragma unroll
    for (int c2 = 0; c2 < 2; c2++) {
      const int ct = wv * 2 + c2;
      const bf16x8 bh = *reinterpret_cast<const bf16x8*>(
          &wpf[(kk * 8 + ct) * 512 + lane * 8]);
      acc2[c2] = __builtin_amdgcn_mfma_f32_16x16x32_bf16(a, bh, acc2[c2], 0, 0, 0);
    }
  }
  // C layout: col = ct*16+lane16, row(b_loc) = quad*4+reg
  float bbv[2], latr[2], latn[2];
#pragma unroll
  for (int c2 = 0; c2 < 2; c2++) bbv[c2] = l1b[(wv * 2 + c2) * 16 + lane16];
#pragma unroll
  for (int reg = 0; reg < 4; reg++) {
    const int r_loc = quad * 4 + reg;
    const int b = bbase + r_loc;
    const int ir  = (cr[b] * 10 + pa[b]) * 128;
    const int in_ = (cn[b] * 10 + pa[b]) * 128;
    float pr = 0.f, pn = 0.f;
#pragma unroll
    for (int c2 = 0; c2 < 2; c2++) {
      const int col = (wv * 2 + c2) * 16 + lane16;
      const float v = fmaxf(acc2[c2][reg] + bbv[c2], 0.f);
      pr = fmaf(v, latTab[ir + col], pr);
      pn = fmaf(v, latTab[in_ + col], pn);
    }
    pr += __shfl_xor(pr, 1, 16); pr += __shfl_xor(pr, 2, 16);
    pr += __shfl_xor(pr, 4, 16); pr += __shfl_xor(pr, 8, 16);
    pn += __shfl_xor(pn, 1, 16); pn += __shfl_xor(pn, 2, 16);
    pn += __shfl_xor(pn, 4, 16); pn += __shfl_xor(pn, 8, 16);
    if (lane16 == 0) {
      atomicAdd(&s_pr[r_loc], pr);
      atomicAdd(&s_pn[r_loc], pn);
    }
  }
  __syncthreads();
  if (tid < 16) {
    out[bbase + tid] = s_pr[tid];
    out[BB + bbase + tid] = s_pn[tid];
  }
}

extern "C" void kernel_launch(void* const* d_in, const int* in_sizes, int n_in,
                              void* d_out, int out_size, void* d_ws, size_t ws_size,
                              hipStream_t stream) {
  const float* feat  = (const float*)d_in[0];   // [N,F]
  const float* adj   = (const float*)d_in[1];   // [M,N]
  const int*   hist  = (const int*)d_in[2];     // [B,K]
  // d_in[3] item_id unused by reference
  const int*   cr    = (const int*)d_in[4];
  const int*   cn    = (const int*)d_in[5];
  const int*   pa    = (const int*)d_in[6];
  const float* wemb  = (const float*)d_in[7];   // [F,D]
  const float* bemb  = (const float*)d_in[8];   // [D]
  const float* wchar = (const float*)d_in[9];   // [2D,D]
  const float* attw  = (const float*)d_in[10];  // [D]
  const float* attb  = (const float*)d_in[11];  // [1]
  const float* l1w   = (const float*)d_in[12];  // [2D,D]
  const float* l1b   = (const float*)d_in[13];  // [D]
  float* out = (float*)d_out;
  float* ws  = (float*)d_ws;

  float* q     = ws + OFF_Q;
  float* cerep = ws + OFF_CEREP;
  float* lat   = ws + OFF_LAT;
  float* ce01p = ws + OFF_CE01;
  float* cs    = ws + OFF_CS;
  unsigned char* fe8 = (unsigned char*)(ws + OFF_FE8);
  short* wf    = (short*)(ws + OFF_WF);
  short* wpf   = (short*)(ws + OFF_WPF);

  k0_wprep<<<24, 256, 0, stream>>>(wemb, l1w, wf, wpf, cerep);
  k1_fused<<<NB1, 256, 0, stream>>>(feat, wf, bemb, attw, adj, q, fe8, cerep);
  k3_prep<<<21, 128, 0, stream>>>(cerep, wchar, attw, lat, ce01p, cs);
  k4_fused<<<2048, 256, 0, stream>>>(fe8, q, adj, hist, cs, attb, ce01p,
                                     wpf, l1b, lat, cr, cn, pa, out);
}